// Round 3
// baseline (4850.379 us; speedup 1.0000x reference)
//
#include <hip/hip_runtime.h>
#include <hip/hip_bf16.h>
#include <cstdint>

#define B_   2048
#define H_   512
#define T_   128
#define V_   64
#define FOURH 2048

typedef __bf16 bf16x8 __attribute__((ext_vector_type(8)));
typedef float  floatx4 __attribute__((ext_vector_type(4)));

__device__ __forceinline__ unsigned short f2bf(float f) {
    union { float f; uint32_t u; } v; v.f = f;
    uint32_t r = v.u + 0x7fff + ((v.u >> 16) & 1);
    return (unsigned short)(r >> 16);
}

__device__ __forceinline__ float sigmoidf_(float x) {
    return 1.0f / (1.0f + __expf(-x));
}
__device__ __forceinline__ float tanhf_(float x) {
    float e = __expf(fminf(-2.0f * x, 80.0f));
    return (1.0f - e) / (1.0f + e);
}

__device__ __forceinline__ void global_to_lds16(const unsigned short* g, unsigned short* l) {
    __builtin_amdgcn_global_load_lds(
        (const __attribute__((address_space(1))) unsigned int*)g,
        (__attribute__((address_space(3))) unsigned int*)l, 16, 0, 0);
}

// ---------------------------------------------------------------------------
// prep: permuted bf16 weights, bf16 z / fc_w, fused permuted bias, zero flags.
// Tile-col layout (per j, 128 cols): c = 64*wn + 16*gate + ln,
// maps to original gate row p = gate*512 + j*32 + (wn*16 + ln).
// ---------------------------------------------------------------------------
__global__ void prep_kernel(const float* __restrict__ z,
                            const float* __restrict__ w_ih,
                            const float* __restrict__ w_hh,
                            const float* __restrict__ b_ih,
                            const float* __restrict__ b_hh,
                            const float* __restrict__ fc_w,
                            unsigned short* __restrict__ Bp_ih,
                            unsigned short* __restrict__ Bp_hh,
                            unsigned short* __restrict__ z_bf,
                            unsigned short* __restrict__ fcw_bf,
                            float* __restrict__ biasp,
                            unsigned int* __restrict__ cnt) {
    int i = blockIdx.x * blockDim.x + threadIdx.x;   // 2048*512 threads
    int col = i >> 9, k = i & 511;
    int jj = col >> 7, cc = col & 127;
    int gate = (cc >> 4) & 3;
    int hcl = ((cc >> 6) << 4) | (cc & 15);
    int p = gate * 512 + jj * 32 + hcl;
    Bp_hh[i] = f2bf(w_hh[p * 512 + k]);
    Bp_ih[i] = f2bf(w_ih[p * 512 + k]);
    z_bf[i]  = f2bf(z[i]);
    if (i < V_ * H_) fcw_bf[i] = f2bf(fc_w[i]);
    if (i < FOURH) {
        int j2 = i >> 7, c2 = i & 127;
        int g2 = (c2 >> 4) & 3;
        int h2 = ((c2 >> 6) << 4) | (c2 & 15);
        int p2 = g2 * 512 + j2 * 32 + h2;
        biasp[i] = b_ih[p2] + b_hh[p2];
    }
    if (blockIdx.x == 0 && threadIdx.x < 16) cnt[threadIdx.x] = 0;
}

// ---------------------------------------------------------------------------
// Round-1-proven 128x128 (K=512, BK=64) tile core for the x-gates GEMM.
// ---------------------------------------------------------------------------
__device__ __forceinline__ void gemm_tile_r1(
        const unsigned short* __restrict__ Aglob,
        const unsigned short* __restrict__ Bglob,
        int arow0, int brow0,
        unsigned short* As, unsigned short* Bs,
        floatx4 acc[2][8], int w, int l) {
    const int lr = l >> 3;
    const int gl = (l & 7) ^ lr;
    const int ln = l & 15, lq = l >> 4, ls = l & 7;
    for (int kc = 0; kc < 8; ++kc) {
        const int kof = kc * 64 + gl * 8;
        #pragma unroll
        for (int q = 0; q < 4; ++q) {
            const int r0 = (w * 4 + q) * 8;
            global_to_lds16(Aglob + (size_t)(arow0 + r0 + lr) * 512 + kof, As + r0 * 64);
            global_to_lds16(Bglob + (size_t)(brow0 + r0 + lr) * 512 + kof, Bs + r0 * 64);
        }
        __syncthreads();
        #pragma unroll
        for (int kk = 0; kk < 2; ++kk) {
            bf16x8 a[2], b[8];
            #pragma unroll
            for (int mt = 0; mt < 2; ++mt) {
                const int m = 32 * w + 16 * mt + ln;
                const int g = kk * 4 + lq;
                a[mt] = *(const bf16x8*)(As + m * 64 + ((g ^ ls) * 8));
            }
            #pragma unroll
            for (int nt = 0; nt < 8; ++nt) {
                const int n = 16 * nt + ln;
                const int g = kk * 4 + lq;
                b[nt] = *(const bf16x8*)(Bs + n * 64 + ((g ^ ls) * 8));
            }
            #pragma unroll
            for (int mt = 0; mt < 2; ++mt)
                #pragma unroll
                for (int nt = 0; nt < 8; ++nt)
                    acc[mt][nt] = __builtin_amdgcn_mfma_f32_16x16x32_bf16(
                        a[mt], b[nt], acc[mt][nt], 0, 0, 0);
        }
        __syncthreads();
    }
}

__global__ void __launch_bounds__(256) xg_gemm_kernel(
        const unsigned short* __restrict__ z_bf,
        const unsigned short* __restrict__ Bp_ih,
        const float* __restrict__ biasp,
        float* __restrict__ xg) {
    __shared__ unsigned short As[128 * 64];
    __shared__ unsigned short Bs[128 * 64];
    const int bi = blockIdx.x, j = blockIdx.y;
    const int tid = threadIdx.x, w = tid >> 6, l = tid & 63;
    floatx4 acc[2][8];
    const floatx4 zf = {0.f, 0.f, 0.f, 0.f};
    for (int a1 = 0; a1 < 2; ++a1) for (int a2 = 0; a2 < 8; ++a2) acc[a1][a2] = zf;

    gemm_tile_r1(z_bf, Bp_ih, bi * 128, j * 128, As, Bs, acc, w, l);

    const int ln = l & 15, lq = l >> 4;
    #pragma unroll
    for (int mt = 0; mt < 2; ++mt)
        #pragma unroll
        for (int nt = 0; nt < 8; ++nt) {
            const int colp = j * 128 + nt * 16 + ln;
            const float bv = biasp[colp];
            #pragma unroll
            for (int r = 0; r < 4; ++r) {
                const int b = bi * 128 + 32 * w + 16 * mt + lq * 4 + r;
                xg[(size_t)b * FOURH + colp] = acc[mt][nt][r] + bv;
            }
        }
}

// ---------------------------------------------------------------------------
// A staging: As[row 0..127][8 granules of 16B], slot s of row r holds
// granule s ^ (r&7)  (same scheme as the round-1 passing kernel).
// ---------------------------------------------------------------------------
__device__ __forceinline__ void stage_A(const unsigned short* __restrict__ Aglob, int arow0,
                                        int kc, unsigned short* As, int w, int l) {
    const int lr = l >> 3;
    const int gl = (l & 7) ^ lr;
    const int kof = kc * 64 + gl * 8;
    #pragma unroll
    for (int q = 0; q < 4; ++q) {
        const int r0 = (w * 4 + q) * 8;
        global_to_lds16(Aglob + (size_t)(arow0 + r0 + lr) * 512 + kof, As + r0 * 64);
    }
}

// ---------------------------------------------------------------------------
// Persistent LSTM. Plain launch, 256 WGs (1/CU by capacity). WG=(bi,j);
// 16 WGs per bi form an independent pipeline synced by flag cnt[bi].
// w_hh tile in REGISTERS (bq[16][4] per wave); LDS only A double-buffer.
// ---------------------------------------------------------------------------
__global__ void __launch_bounds__(256, 1) lstm_persistent(
        const unsigned short* __restrict__ Bp_hh,
        const unsigned short* __restrict__ fcw_bf,
        const float* __restrict__ xg,
        const float* __restrict__ fc_b,
        unsigned short* __restrict__ h0b,
        unsigned short* __restrict__ h1b,
        unsigned int* __restrict__ cnt,
        float* __restrict__ out) {
    __shared__ unsigned short As0[128 * 64];   // 16 KiB
    __shared__ unsigned short As1[128 * 64];   // 16 KiB

    const int bx = blockIdx.x;
    const int bi = bx & 15;        // bx%8 == bi%8 for all j -> bi-group stays on one XCD
    const int j  = bx >> 4;
    const int tid = threadIdx.x;
    const int w = tid >> 6, l = tid & 63;
    const int wm = w >> 1, wn = w & 1;
    const int ln = l & 15, lq = l >> 4;
    const bool jlt8 = (j < 8);
    const int j16 = j * 16;
    const int v = 16 * w + ln;
    const float fcb_v = fc_b[v];
    const int arow0 = bi * 128;
    unsigned int* cntp = cnt + bi;
    const floatx4 zf = {0.f, 0.f, 0.f, 0.f};

    // ---- load recurrent-weight fragments into registers (persistent) ----
    // bq[s][nt]: B row n = j*128 + 64*wn + 16*nt + ln, k = 32*s + 8*lq .. +8
    bf16x8 bq[16][4];
    {
        const unsigned short* bbase =
            Bp_hh + ((size_t)(j * 128 + 64 * wn + ln)) * 512 + lq * 8;
        #pragma unroll
        for (int s = 0; s < 16; ++s)
            #pragma unroll
            for (int nt = 0; nt < 4; ++nt)
                bq[s][nt] = *(const bf16x8*)(bbase + (size_t)nt * 16 * 512 + s * 32);
    }

    // ---- load x-gate tile into registers ----
    floatx4 xga[4][4];
    #pragma unroll
    for (int mt = 0; mt < 4; ++mt)
        #pragma unroll
        for (int nt = 0; nt < 4; ++nt)
            #pragma unroll
            for (int r = 0; r < 4; ++r) {
                const int b = arow0 + 64 * wm + 16 * mt + lq * 4 + r;
                xga[mt][nt][r] = xg[(size_t)b * FOURH + j * 128 + 64 * wn + 16 * nt + ln];
            }

    // ---- t = 0: c0 = 0 -> c = i*g, h = o*tanh(c) ----
    float cst[4][4];
    const int hc = j * 32 + wn * 16 + ln;
    #pragma unroll
    for (int mt = 0; mt < 4; ++mt)
        #pragma unroll
        for (int r = 0; r < 4; ++r) {
            float iv = sigmoidf_(xga[mt][0][r]);
            float gv = tanhf_  (xga[mt][2][r]);
            float ov = sigmoidf_(xga[mt][3][r]);
            float cv = iv * gv;
            cst[mt][r] = cv;
            const int b = arow0 + 64 * wm + 16 * mt + lq * 4 + r;
            h0b[(size_t)b * 512 + hc] = f2bf(ov * tanhf_(cv));
        }
    __syncthreads();                 // drains each wave's stores to L2
    if (tid == 0) {
        __threadfence();             // L2 writeback to coherence point
        __hip_atomic_fetch_add(cntp, 1u, __ATOMIC_RELEASE, __HIP_MEMORY_SCOPE_AGENT);
    }

    unsigned short* hb[2] = {h0b, h1b};
    for (int t = 1; t < T_; ++t) {
        // wait for all 16 WGs of this bi-group to publish h_{t-1}
        if (tid == 0) {
            const unsigned int tgt = 16u * (unsigned int)t;
            while (__hip_atomic_fetch_add(cntp, 0u, __ATOMIC_RELAXED,
                                          __HIP_MEMORY_SCOPE_AGENT) < tgt)
                __builtin_amdgcn_s_sleep(2);
            __threadfence();         // invalidate stale L1/L2 before h reads
        }
        __syncthreads();

        const unsigned short* hprev = hb[(t - 1) & 1];
        unsigned short* hnext = hb[t & 1];

        floatx4 acc[4][4];
        #pragma unroll
        for (int a1 = 0; a1 < 4; ++a1)
            #pragma unroll
            for (int a2 = 0; a2 < 4; ++a2) acc[a1][a2] = zf;
        floatx4 pacc = zf;

        stage_A(hprev, arow0, 0, As0, w, l);
        __syncthreads();
        #pragma unroll
        for (int kc = 0; kc < 8; ++kc) {
            const unsigned short* Ac = ((kc & 1) == 0) ? As0 : As1;
            unsigned short* Ast      = ((kc & 1) == 0) ? As1 : As0;
            if (kc < 7) stage_A(hprev, arow0, kc + 1, Ast, w, l);
            #pragma unroll
            for (int kk = 0; kk < 2; ++kk) {
                const int s = kc * 2 + kk;
                const int ga = kk * 4 + lq;
                bf16x8 af[4];
                #pragma unroll
                for (int mt = 0; mt < 4; ++mt) {
                    const int m = 64 * wm + 16 * mt + ln;
                    af[mt] = *(const bf16x8*)(Ac + m * 64 + ((ga ^ (ln & 7)) * 8));
                }
                #pragma unroll
                for (int mt = 0; mt < 4; ++mt)
                    #pragma unroll
                    for (int nt = 0; nt < 4; ++nt)
                        acc[mt][nt] = __builtin_amdgcn_mfma_f32_16x16x32_bf16(
                            af[mt], bq[s][nt], acc[mt][nt], 0, 0, 0);
                if (jlt8) {
                    bf16x8 ap = *(const bf16x8*)(Ac + (j16 + ln) * 64 + ((ga ^ (ln & 7)) * 8));
                    bf16x8 bp = *(const bf16x8*)(fcw_bf + (size_t)v * 512 + s * 32 + lq * 8);
                    pacc = __builtin_amdgcn_mfma_f32_16x16x32_bf16(ap, bp, pacc, 0, 0, 0);
                }
            }
            __syncthreads();
        }

        // cell update epilogue, all in registers
        #pragma unroll
        for (int mt = 0; mt < 4; ++mt)
            #pragma unroll
            for (int r = 0; r < 4; ++r) {
                float iv = sigmoidf_(acc[mt][0][r] + xga[mt][0][r]);
                float fv = sigmoidf_(acc[mt][1][r] + xga[mt][1][r]);
                float gv = tanhf_  (acc[mt][2][r] + xga[mt][2][r]);
                float ov = sigmoidf_(acc[mt][3][r] + xga[mt][3][r]);
                float cn = fv * cst[mt][r] + iv * gv;
                cst[mt][r] = cn;
                const int b = arow0 + 64 * wm + 16 * mt + lq * 4 + r;
                hnext[(size_t)b * 512 + hc] = f2bf(ov * tanhf_(cn));
            }
        __syncthreads();
        if (tid == 0) {
            __threadfence();
            __hip_atomic_fetch_add(cntp, 1u, __ATOMIC_RELEASE, __HIP_MEMORY_SCOPE_AGENT);
        }

        // projection of h_{t-1} (accumulated in gemm above) -> out[:, t-1, :]
        if (jlt8) {
            #pragma unroll
            for (int r = 0; r < 4; ++r) {
                const int b = arow0 + j16 + lq * 4 + r;
                out[(size_t)b * (T_ * V_) + (t - 1) * V_ + v] = fmaxf(pacc[r] + fcb_v, 0.0f);
            }
        }
    }

    // ---- final projection of h_{T-1} ----
    if (tid == 0) {
        const unsigned int tgt = 16u * (unsigned int)T_;
        while (__hip_atomic_fetch_add(cntp, 0u, __ATOMIC_RELAXED,
                                      __HIP_MEMORY_SCOPE_AGENT) < tgt)
            __builtin_amdgcn_s_sleep(2);
        __threadfence();
    }
    __syncthreads();
    if (jlt8) {
        const unsigned short* hlast = hb[(T_ - 1) & 1];
        floatx4 pa = zf;
        const int ar = arow0 + j16 + ln;
        #pragma unroll
        for (int kc = 0; kc < 16; ++kc) {
            const int k = kc * 32 + lq * 8;
            bf16x8 a = *(const bf16x8*)(hlast + (size_t)ar * 512 + k);
            bf16x8 b = *(const bf16x8*)(fcw_bf + (size_t)v * 512 + k);
            pa = __builtin_amdgcn_mfma_f32_16x16x32_bf16(a, b, pa, 0, 0, 0);
        }
        #pragma unroll
        for (int r = 0; r < 4; ++r) {
            const int b = arow0 + j16 + lq * 4 + r;
            out[(size_t)b * (T_ * V_) + (T_ - 1) * V_ + v] = fmaxf(pa[r] + fcb_v, 0.0f);
        }
    }
}

// ---------------------------------------------------------------------------
extern "C" void kernel_launch(void* const* d_in, const int* in_sizes, int n_in,
                              void* d_out, int out_size, void* d_ws, size_t ws_size,
                              hipStream_t stream) {
    const float* z    = (const float*)d_in[0];
    const float* w_ih = (const float*)d_in[1];
    const float* w_hh = (const float*)d_in[2];
    const float* b_ih = (const float*)d_in[3];
    const float* b_hh = (const float*)d_in[4];
    const float* fc_w = (const float*)d_in[5];
    const float* fc_b = (const float*)d_in[6];
    float* out = (float*)d_out;

    char* ws = (char*)d_ws;
    size_t o = 0;
    auto take = [&](size_t bytes) { char* p = ws + o; o += (bytes + 255) & ~(size_t)255; return p; };
    unsigned short* Bp_hh  = (unsigned short*)take((size_t)FOURH * H_ * 2);
    unsigned short* Bp_ih  = (unsigned short*)take((size_t)FOURH * H_ * 2);
    unsigned short* z_bf   = (unsigned short*)take((size_t)B_ * H_ * 2);
    unsigned short* fcw_bf = (unsigned short*)take((size_t)V_ * H_ * 2);
    float*          biasp  = (float*)take((size_t)FOURH * 4);
    unsigned short* hbuf0  = (unsigned short*)take((size_t)B_ * H_ * 2);
    unsigned short* hbuf1  = (unsigned short*)take((size_t)B_ * H_ * 2);
    unsigned int*   cnt    = (unsigned int*)take(64);
    float*          xg     = (float*)take((size_t)B_ * FOURH * 4);

    prep_kernel<<<(B_ * H_) / 256, 256, 0, stream>>>(z, w_ih, w_hh, b_ih, b_hh, fc_w,
                                                     Bp_ih, Bp_hh, z_bf, fcw_bf, biasp, cnt);
    xg_gemm_kernel<<<dim3(16, 16), 256, 0, stream>>>(z_bf, Bp_ih, biasp, xg);
    lstm_persistent<<<256, 256, 0, stream>>>(Bp_hh, fcw_bf, xg, fc_b,
                                             hbuf0, hbuf1, cnt, out);
}

// Round 4
// 1657.781 us; speedup vs baseline: 2.9258x; 2.9258x over previous
//
#include <hip/hip_runtime.h>
#include <hip/hip_bf16.h>
#include <cstdint>

#define B_   2048
#define H_   512
#define T_   128
#define V_   64
#define FOURH 2048

typedef __bf16 bf16x8 __attribute__((ext_vector_type(8)));
typedef float  floatx4 __attribute__((ext_vector_type(4)));
typedef int    intx4   __attribute__((ext_vector_type(4)));

__device__ __forceinline__ unsigned short f2bf(float f) {
    union { float f; uint32_t u; } v; v.f = f;
    uint32_t r = v.u + 0x7fff + ((v.u >> 16) & 1);
    return (unsigned short)(r >> 16);
}

__device__ __forceinline__ float sigmoidf_(float x) {
    return 1.0f / (1.0f + __expf(-x));
}
__device__ __forceinline__ float tanhf_(float x) {
    float e = __expf(fminf(-2.0f * x, 80.0f));
    return (1.0f - e) / (1.0f + e);
}

__device__ __forceinline__ void global_to_lds16(const unsigned short* g, unsigned short* l) {
    __builtin_amdgcn_global_load_lds(
        (const __attribute__((address_space(1))) unsigned int*)g,
        (__attribute__((address_space(3))) unsigned int*)l, 16, 0, 0);
}

// System-coherent 16B load (bypass L1+L2, read IF$ — cross-XCD safe), blocking.
__device__ __forceinline__ bf16x8 load16_sys(const unsigned short* p) {
    bf16x8 d;
    asm volatile("global_load_dwordx4 %0, %1, off sc0 sc1\n\t"
                 "s_waitcnt vmcnt(0)"
                 : "=v"(d) : "v"(p));
    return d;
}

// ---------------------------------------------------------------------------
// prep: permuted bf16 weights, bf16 z / fc_w, fused permuted bias, zero flags.
// Tile-col layout (per j, 128 cols): c = 64*wn + 16*gate + ln,
// maps to original gate row p = gate*512 + j*32 + (wn*16 + ln).
// ---------------------------------------------------------------------------
__global__ void prep_kernel(const float* __restrict__ z,
                            const float* __restrict__ w_ih,
                            const float* __restrict__ w_hh,
                            const float* __restrict__ b_ih,
                            const float* __restrict__ b_hh,
                            const float* __restrict__ fc_w,
                            unsigned short* __restrict__ Bp_ih,
                            unsigned short* __restrict__ Bp_hh,
                            unsigned short* __restrict__ z_bf,
                            unsigned short* __restrict__ fcw_bf,
                            float* __restrict__ biasp,
                            unsigned int* __restrict__ cnt) {
    int i = blockIdx.x * blockDim.x + threadIdx.x;   // 2048*512 threads
    int col = i >> 9, k = i & 511;
    int jj = col >> 7, cc = col & 127;
    int gate = (cc >> 4) & 3;
    int hcl = ((cc >> 6) << 4) | (cc & 15);
    int p = gate * 512 + jj * 32 + hcl;
    Bp_hh[i] = f2bf(w_hh[p * 512 + k]);
    Bp_ih[i] = f2bf(w_ih[p * 512 + k]);
    z_bf[i]  = f2bf(z[i]);
    if (i < V_ * H_) fcw_bf[i] = f2bf(fc_w[i]);
    if (i < FOURH) {
        int j2 = i >> 7, c2 = i & 127;
        int g2 = (c2 >> 4) & 3;
        int h2 = ((c2 >> 6) << 4) | (c2 & 15);
        int p2 = g2 * 512 + j2 * 32 + h2;
        biasp[i] = b_ih[p2] + b_hh[p2];
    }
    // flag counters padded to 128B each (atomic contention isolation)
    if (blockIdx.x == 0 && threadIdx.x < 16) cnt[threadIdx.x * 32] = 0;
}

// ---------------------------------------------------------------------------
// Round-1-proven 128x128 (K=512, BK=64) tile core for the x-gates GEMM.
// ---------------------------------------------------------------------------
__device__ __forceinline__ void gemm_tile_r1(
        const unsigned short* __restrict__ Aglob,
        const unsigned short* __restrict__ Bglob,
        int arow0, int brow0,
        unsigned short* As, unsigned short* Bs,
        floatx4 acc[2][8], int w, int l) {
    const int lr = l >> 3;
    const int gl = (l & 7) ^ lr;
    const int ln = l & 15, lq = l >> 4, ls = l & 7;
    for (int kc = 0; kc < 8; ++kc) {
        const int kof = kc * 64 + gl * 8;
        #pragma unroll
        for (int q = 0; q < 4; ++q) {
            const int r0 = (w * 4 + q) * 8;
            global_to_lds16(Aglob + (size_t)(arow0 + r0 + lr) * 512 + kof, As + r0 * 64);
            global_to_lds16(Bglob + (size_t)(brow0 + r0 + lr) * 512 + kof, Bs + r0 * 64);
        }
        __syncthreads();
        #pragma unroll
        for (int kk = 0; kk < 2; ++kk) {
            bf16x8 a[2], b[8];
            #pragma unroll
            for (int mt = 0; mt < 2; ++mt) {
                const int m = 32 * w + 16 * mt + ln;
                const int g = kk * 4 + lq;
                a[mt] = *(const bf16x8*)(As + m * 64 + ((g ^ ls) * 8));
            }
            #pragma unroll
            for (int nt = 0; nt < 8; ++nt) {
                const int n = 16 * nt + ln;
                const int g = kk * 4 + lq;
                b[nt] = *(const bf16x8*)(Bs + n * 64 + ((g ^ ls) * 8));
            }
            #pragma unroll
            for (int mt = 0; mt < 2; ++mt)
                #pragma unroll
                for (int nt = 0; nt < 8; ++nt)
                    acc[mt][nt] = __builtin_amdgcn_mfma_f32_16x16x32_bf16(
                        a[mt], b[nt], acc[mt][nt], 0, 0, 0);
        }
        __syncthreads();
    }
}

__global__ void __launch_bounds__(256) xg_gemm_kernel(
        const unsigned short* __restrict__ z_bf,
        const unsigned short* __restrict__ Bp_ih,
        const float* __restrict__ biasp,
        float* __restrict__ xg) {
    __shared__ unsigned short As[128 * 64];
    __shared__ unsigned short Bs[128 * 64];
    const int bi = blockIdx.x, j = blockIdx.y;
    const int tid = threadIdx.x, w = tid >> 6, l = tid & 63;
    floatx4 acc[2][8];
    const floatx4 zf = {0.f, 0.f, 0.f, 0.f};
    for (int a1 = 0; a1 < 2; ++a1) for (int a2 = 0; a2 < 8; ++a2) acc[a1][a2] = zf;

    gemm_tile_r1(z_bf, Bp_ih, bi * 128, j * 128, As, Bs, acc, w, l);

    const int ln = l & 15, lq = l >> 4;
    #pragma unroll
    for (int mt = 0; mt < 2; ++mt)
        #pragma unroll
        for (int nt = 0; nt < 8; ++nt) {
            const int colp = j * 128 + nt * 16 + ln;
            const float bv = biasp[colp];
            #pragma unroll
            for (int r = 0; r < 4; ++r) {
                const int b = bi * 128 + 32 * w + 16 * mt + lq * 4 + r;
                xg[(size_t)b * FOURH + colp] = acc[mt][nt][r] + bv;
            }
        }
}

// ---------------------------------------------------------------------------
// A staging split into issue (async sc0/sc1 loads into VGPRs) and commit
// (waitcnt + ds_write_b128). LDS layout identical to the round-3 kernel:
// As[row 0..127][8 slots of 16B], slot s of row r holds granule s^(r&7).
// ---------------------------------------------------------------------------
__device__ __forceinline__ void stage_issue(const unsigned short* __restrict__ Aglob,
                                            int arow0, int kc, int w, int l,
                                            intx4& t0, intx4& t1, intx4& t2, intx4& t3) {
    const int lr = l >> 3;
    const int gl = (l & 7) ^ lr;
    const int kof = kc * 64 + gl * 8;
    const unsigned short* p0 = Aglob + (size_t)(arow0 + (w * 4 + 0) * 8 + lr) * 512 + kof;
    const unsigned short* p1 = Aglob + (size_t)(arow0 + (w * 4 + 1) * 8 + lr) * 512 + kof;
    const unsigned short* p2 = Aglob + (size_t)(arow0 + (w * 4 + 2) * 8 + lr) * 512 + kof;
    const unsigned short* p3 = Aglob + (size_t)(arow0 + (w * 4 + 3) * 8 + lr) * 512 + kof;
    asm volatile(
        "global_load_dwordx4 %0, %4, off sc0 sc1\n\t"
        "global_load_dwordx4 %1, %5, off sc0 sc1\n\t"
        "global_load_dwordx4 %2, %6, off sc0 sc1\n\t"
        "global_load_dwordx4 %3, %7, off sc0 sc1"
        : "=&v"(t0), "=&v"(t1), "=&v"(t2), "=&v"(t3)
        : "v"(p0), "v"(p1), "v"(p2), "v"(p3)
        : "memory");
}

__device__ __forceinline__ void stage_commit(unsigned short* As, int w, int l,
                                             intx4 t0, intx4 t1, intx4 t2, intx4 t3) {
    asm volatile("s_waitcnt vmcnt(0)" ::: "memory");
    const int lr = l >> 3, sl = (l & 7) * 8;
    *(intx4*)(As + ((w * 4 + 0) * 8 + lr) * 64 + sl) = t0;
    *(intx4*)(As + ((w * 4 + 1) * 8 + lr) * 64 + sl) = t1;
    *(intx4*)(As + ((w * 4 + 2) * 8 + lr) * 64 + sl) = t2;
    *(intx4*)(As + ((w * 4 + 3) * 8 + lr) * 64 + sl) = t3;
}

// ---------------------------------------------------------------------------
// Persistent LSTM. Plain launch, 256 WGs (all co-resident by capacity).
// WG=(bi,j); 16 WGs per bi synced by padded flag cnt[bi*32] using RELAXED
// atomics only. h passes through the (cross-XCD coherent) Infinity Cache via
// sc0/sc1 write-through stores + sc0/sc1 bypass loads — NO cache-wide fences.
// ---------------------------------------------------------------------------
__global__ void __launch_bounds__(256, 1) lstm_persistent(
        const unsigned short* __restrict__ Bp_hh,
        const unsigned short* __restrict__ fcw_bf,
        const float* __restrict__ xg,
        const float* __restrict__ fc_b,
        unsigned short* __restrict__ h0b,
        unsigned short* __restrict__ h1b,
        unsigned int* __restrict__ cnt,
        float* __restrict__ out) {
    __shared__ unsigned short As0[128 * 64];   // 16 KiB (also reused as h transpose buf)
    __shared__ unsigned short As1[128 * 64];   // 16 KiB

    const int bx = blockIdx.x;
    const int bi = bx & 15;        // bx%8 == bi%8 for all j -> group L2 locality (perf only)
    const int j  = bx >> 4;
    const int tid = threadIdx.x;
    const int w = tid >> 6, l = tid & 63;
    const int wm = w >> 1, wn = w & 1;
    const int ln = l & 15, lq = l >> 4;
    const bool jlt8 = (j < 8);
    const int j16 = j * 16;
    const int v = 16 * w + ln;
    const float fcb_v = fc_b[v];
    const int arow0 = bi * 128;
    unsigned int* cntp = cnt + bi * 32;        // 128B-padded counters
    const floatx4 zf = {0.f, 0.f, 0.f, 0.f};

    // ---- recurrent-weight fragments in registers (persistent, 256 VGPRs) ----
    // bq[s][nt]: B row n = j*128 + 64*wn + 16*nt + ln, k = 32*s + 8*lq .. +8
    bf16x8 bq[16][4];
    {
        const unsigned short* bbase =
            Bp_hh + ((size_t)(j * 128 + 64 * wn + ln)) * 512 + lq * 8;
        #pragma unroll
        for (int s = 0; s < 16; ++s)
            #pragma unroll
            for (int nt = 0; nt < 4; ++nt)
                bq[s][nt] = *(const bf16x8*)(bbase + (size_t)nt * 16 * 512 + s * 32);
    }

    // ---- x-gate tile into registers ----
    floatx4 xga[4][4];
    #pragma unroll
    for (int mt = 0; mt < 4; ++mt)
        #pragma unroll
        for (int nt = 0; nt < 4; ++nt)
            #pragma unroll
            for (int r = 0; r < 4; ++r) {
                const int b = arow0 + 64 * wm + 16 * mt + lq * 4 + r;
                xga[mt][nt][r] = xg[(size_t)b * FOURH + j * 128 + 64 * wn + 16 * nt + ln];
            }

    // h store helper state: this WG owns h cols [j*32, j*32+32)
    unsigned short* hlds = As0;                 // 128 rows x 32 cols ushort = 8 KB

    // ---- t = 0: c0 = 0 -> c = i*g, h = o*tanh(c) ----
    float cst[4][4];
    #pragma unroll
    for (int mt = 0; mt < 4; ++mt)
        #pragma unroll
        for (int r = 0; r < 4; ++r) {
            float iv = sigmoidf_(xga[mt][0][r]);
            float gv = tanhf_  (xga[mt][2][r]);
            float ov = sigmoidf_(xga[mt][3][r]);
            float cv = iv * gv;
            cst[mt][r] = cv;
            hlds[(64 * wm + 16 * mt + lq * 4 + r) * 32 + (wn * 16 + ln)] = f2bf(ov * tanhf_(cv));
        }
    __syncthreads();
    for (int c = tid; c < 512; c += 256) {      // 512 x 16B coherent stores
        const int row = c >> 2, seg = c & 3;
        intx4 d = *(const intx4*)(hlds + row * 32 + seg * 8);
        const unsigned short* p = h0b + (size_t)(arow0 + row) * 512 + j * 32 + seg * 8;
        asm volatile("global_store_dwordx4 %0, %1, off sc0 sc1" :: "v"(p), "v"(d) : "memory");
    }
    asm volatile("s_waitcnt vmcnt(0)" ::: "memory");
    __syncthreads();
    if (tid == 0)
        __hip_atomic_fetch_add(cntp, 1u, __ATOMIC_RELAXED, __HIP_MEMORY_SCOPE_AGENT);

    unsigned short* hb[2] = {h0b, h1b};
    #pragma unroll 1
    for (int t = 1; t < T_; ++t) {
        // wait until all 16 WGs of this bi-group published h_{t-1}
        if (tid == 0) {
            const unsigned int tgt = 16u * (unsigned int)t;
            while (__hip_atomic_fetch_add(cntp, 0u, __ATOMIC_RELAXED,
                                          __HIP_MEMORY_SCOPE_AGENT) < tgt)
                __builtin_amdgcn_s_sleep(2);
        }
        __syncthreads();

        const unsigned short* hprev = hb[(t - 1) & 1];
        unsigned short* hnext = hb[t & 1];

        floatx4 acc[4][4];
        #pragma unroll
        for (int a1 = 0; a1 < 4; ++a1)
            #pragma unroll
            for (int a2 = 0; a2 < 4; ++a2) acc[a1][a2] = zf;
        floatx4 pacc = zf;

        intx4 t0, t1, t2, t3;
        stage_issue(hprev, arow0, 0, w, l, t0, t1, t2, t3);
        stage_commit(As0, w, l, t0, t1, t2, t3);
        __syncthreads();
        #pragma unroll
        for (int kc = 0; kc < 8; ++kc) {
            const unsigned short* Ac = ((kc & 1) == 0) ? As0 : As1;
            unsigned short* Ast      = ((kc & 1) == 0) ? As1 : As0;
            if (kc < 7) stage_issue(hprev, arow0, kc + 1, w, l, t0, t1, t2, t3);
            #pragma unroll
            for (int kk = 0; kk < 2; ++kk) {
                const int s = kc * 2 + kk;
                const int ga = kk * 4 + lq;
                bf16x8 af[4];
                #pragma unroll
                for (int mt = 0; mt < 4; ++mt) {
                    const int m = 64 * wm + 16 * mt + ln;
                    af[mt] = *(const bf16x8*)(Ac + m * 64 + ((ga ^ (ln & 7)) * 8));
                }
                #pragma unroll
                for (int mt = 0; mt < 4; ++mt)
                    #pragma unroll
                    for (int nt = 0; nt < 4; ++nt)
                        acc[mt][nt] = __builtin_amdgcn_mfma_f32_16x16x32_bf16(
                            af[mt], bq[s][nt], acc[mt][nt], 0, 0, 0);
                if (jlt8) {
                    bf16x8 ap = *(const bf16x8*)(Ac + (j16 + ln) * 64 + ((ga ^ (ln & 7)) * 8));
                    bf16x8 bp = *(const bf16x8*)(fcw_bf + (size_t)v * 512 + s * 32 + lq * 8);
                    pacc = __builtin_amdgcn_mfma_f32_16x16x32_bf16(ap, bp, pacc, 0, 0, 0);
                }
            }
            if (kc < 7) stage_commit(Ast, w, l, t0, t1, t2, t3);
            __syncthreads();
        }

        // cell update -> h values into LDS transpose buffer (reuse As0)
        #pragma unroll
        for (int mt = 0; mt < 4; ++mt)
            #pragma unroll
            for (int r = 0; r < 4; ++r) {
                float iv = sigmoidf_(acc[mt][0][r] + xga[mt][0][r]);
                float fv = sigmoidf_(acc[mt][1][r] + xga[mt][1][r]);
                float gv = tanhf_  (acc[mt][2][r] + xga[mt][2][r]);
                float ov = sigmoidf_(acc[mt][3][r] + xga[mt][3][r]);
                float cn = fv * cst[mt][r] + iv * gv;
                cst[mt][r] = cn;
                hlds[(64 * wm + 16 * mt + lq * 4 + r) * 32 + (wn * 16 + ln)] = f2bf(ov * tanhf_(cn));
            }
        __syncthreads();
        for (int c = tid; c < 512; c += 256) {
            const int row = c >> 2, seg = c & 3;
            intx4 d = *(const intx4*)(hlds + row * 32 + seg * 8);
            const unsigned short* p = hnext + (size_t)(arow0 + row) * 512 + j * 32 + seg * 8;
            asm volatile("global_store_dwordx4 %0, %1, off sc0 sc1" :: "v"(p), "v"(d) : "memory");
        }
        asm volatile("s_waitcnt vmcnt(0)" ::: "memory");
        __syncthreads();
        if (tid == 0)
            __hip_atomic_fetch_add(cntp, 1u, __ATOMIC_RELAXED, __HIP_MEMORY_SCOPE_AGENT);

        // projection of h_{t-1} (accumulated in the K-loop) -> out[:, t-1, :]
        if (jlt8) {
            #pragma unroll
            for (int r = 0; r < 4; ++r) {
                const int b = arow0 + j16 + lq * 4 + r;
                out[(size_t)b * (T_ * V_) + (t - 1) * V_ + v] = fmaxf(pacc[r] + fcb_v, 0.0f);
            }
        }
    }

    // ---- final projection of h_{T-1} ----
    if (tid == 0) {
        const unsigned int tgt = 16u * (unsigned int)T_;
        while (__hip_atomic_fetch_add(cntp, 0u, __ATOMIC_RELAXED,
                                      __HIP_MEMORY_SCOPE_AGENT) < tgt)
            __builtin_amdgcn_s_sleep(2);
    }
    __syncthreads();
    if (jlt8) {
        const unsigned short* hlast = hb[(T_ - 1) & 1];
        floatx4 pa = zf;
        const int ar = arow0 + j16 + ln;
        #pragma unroll
        for (int kc = 0; kc < 16; ++kc) {
            const int k = kc * 32 + lq * 8;
            bf16x8 a = load16_sys(hlast + (size_t)ar * 512 + k);   // coherent read
            bf16x8 b = *(const bf16x8*)(fcw_bf + (size_t)v * 512 + k);
            pa = __builtin_amdgcn_mfma_f32_16x16x32_bf16(a, b, pa, 0, 0, 0);
        }
        #pragma unroll
        for (int r = 0; r < 4; ++r) {
            const int b = arow0 + j16 + lq * 4 + r;
            out[(size_t)b * (T_ * V_) + (T_ - 1) * V_ + v] = fmaxf(pa[r] + fcb_v, 0.0f);
        }
    }
}

// ---------------------------------------------------------------------------
extern "C" void kernel_launch(void* const* d_in, const int* in_sizes, int n_in,
                              void* d_out, int out_size, void* d_ws, size_t ws_size,
                              hipStream_t stream) {
    const float* z    = (const float*)d_in[0];
    const float* w_ih = (const float*)d_in[1];
    const float* w_hh = (const float*)d_in[2];
    const float* b_ih = (const float*)d_in[3];
    const float* b_hh = (const float*)d_in[4];
    const float* fc_w = (const float*)d_in[5];
    const float* fc_b = (const float*)d_in[6];
    float* out = (float*)d_out;

    char* ws = (char*)d_ws;
    size_t o = 0;
    auto take = [&](size_t bytes) { char* p = ws + o; o += (bytes + 255) & ~(size_t)255; return p; };
    unsigned short* Bp_hh  = (unsigned short*)take((size_t)FOURH * H_ * 2);
    unsigned short* Bp_ih  = (unsigned short*)take((size_t)FOURH * H_ * 2);
    unsigned short* z_bf   = (unsigned short*)take((size_t)B_ * H_ * 2);
    unsigned short* fcw_bf = (unsigned short*)take((size_t)V_ * H_ * 2);
    float*          biasp  = (float*)take((size_t)FOURH * 4);
    unsigned short* hbuf0  = (unsigned short*)take((size_t)B_ * H_ * 2);
    unsigned short* hbuf1  = (unsigned short*)take((size_t)B_ * H_ * 2);
    unsigned int*   cnt    = (unsigned int*)take(16 * 128);
    float*          xg     = (float*)take((size_t)B_ * FOURH * 4);

    prep_kernel<<<(B_ * H_) / 256, 256, 0, stream>>>(z, w_ih, w_hh, b_ih, b_hh, fc_w,
                                                     Bp_ih, Bp_hh, z_bf, fcw_bf, biasp, cnt);
    xg_gemm_kernel<<<dim3(16, 16), 256, 0, stream>>>(z_bf, Bp_ih, biasp, xg);
    lstm_persistent<<<256, 256, 0, stream>>>(Bp_hh, fcw_bf, xg, fc_b,
                                             hbuf0, hbuf1, cnt, out);
}

// Round 5
// 1607.461 us; speedup vs baseline: 3.0174x; 1.0313x over previous
//
#include <hip/hip_runtime.h>
#include <hip/hip_bf16.h>
#include <cstdint>

#define B_   2048
#define H_   512
#define T_   128
#define V_   64
#define FOURH 2048

typedef __bf16 bf16x8 __attribute__((ext_vector_type(8)));
typedef float  floatx4 __attribute__((ext_vector_type(4)));
typedef int    intx4   __attribute__((ext_vector_type(4)));

__device__ __forceinline__ unsigned short f2bf(float f) {
    union { float f; uint32_t u; } v; v.f = f;
    uint32_t r = v.u + 0x7fff + ((v.u >> 16) & 1);
    return (unsigned short)(r >> 16);
}

__device__ __forceinline__ float sigmoidf_(float x) {
    return 1.0f / (1.0f + __expf(-x));
}
__device__ __forceinline__ float tanhf_(float x) {
    float e = __expf(fminf(-2.0f * x, 80.0f));
    return (1.0f - e) / (1.0f + e);
}

__device__ __forceinline__ void global_to_lds16(const unsigned short* g, unsigned short* l) {
    __builtin_amdgcn_global_load_lds(
        (const __attribute__((address_space(1))) unsigned int*)g,
        (__attribute__((address_space(3))) unsigned int*)l, 16, 0, 0);
}

// System-coherent 16B load (bypass L1+L2, read IF$ — cross-XCD safe), blocking.
__device__ __forceinline__ bf16x8 load16_sys(const unsigned short* p) {
    bf16x8 d;
    asm volatile("global_load_dwordx4 %0, %1, off sc0 sc1\n\t"
                 "s_waitcnt vmcnt(0)"
                 : "=v"(d) : "v"(p));
    return d;
}

// ---------------------------------------------------------------------------
// prep: permuted bf16 weights, bf16 z / fc_w, fused permuted bias, zero flags.
// Tile-col layout (per j, 128 cols): c = 64*wn + 16*gate + ln,
// maps to original gate row p = gate*512 + j*32 + (wn*16 + ln).
// ---------------------------------------------------------------------------
__global__ void prep_kernel(const float* __restrict__ z,
                            const float* __restrict__ w_ih,
                            const float* __restrict__ w_hh,
                            const float* __restrict__ b_ih,
                            const float* __restrict__ b_hh,
                            const float* __restrict__ fc_w,
                            unsigned short* __restrict__ Bp_ih,
                            unsigned short* __restrict__ Bp_hh,
                            unsigned short* __restrict__ z_bf,
                            unsigned short* __restrict__ fcw_bf,
                            float* __restrict__ biasp,
                            unsigned int* __restrict__ cnt) {
    int i = blockIdx.x * blockDim.x + threadIdx.x;   // 2048*512 threads
    int col = i >> 9, k = i & 511;
    int jj = col >> 7, cc = col & 127;
    int gate = (cc >> 4) & 3;
    int hcl = ((cc >> 6) << 4) | (cc & 15);
    int p = gate * 512 + jj * 32 + hcl;
    Bp_hh[i] = f2bf(w_hh[p * 512 + k]);
    Bp_ih[i] = f2bf(w_ih[p * 512 + k]);
    z_bf[i]  = f2bf(z[i]);
    if (i < V_ * H_) fcw_bf[i] = f2bf(fc_w[i]);
    if (i < FOURH) {
        int j2 = i >> 7, c2 = i & 127;
        int g2 = (c2 >> 4) & 3;
        int h2 = ((c2 >> 6) << 4) | (c2 & 15);
        int p2 = g2 * 512 + j2 * 32 + h2;
        biasp[i] = b_ih[p2] + b_hh[p2];
    }
    // flag counters padded to 128B each (atomic contention isolation)
    if (blockIdx.x == 0 && threadIdx.x < 16) cnt[threadIdx.x * 32] = 0;
}

// ---------------------------------------------------------------------------
// Round-1-proven 128x128 (K=512, BK=64) tile core for the x-gates GEMM.
// ---------------------------------------------------------------------------
__device__ __forceinline__ void gemm_tile_r1(
        const unsigned short* __restrict__ Aglob,
        const unsigned short* __restrict__ Bglob,
        int arow0, int brow0,
        unsigned short* As, unsigned short* Bs,
        floatx4 acc[2][8], int w, int l) {
    const int lr = l >> 3;
    const int gl = (l & 7) ^ lr;
    const int ln = l & 15, lq = l >> 4, ls = l & 7;
    for (int kc = 0; kc < 8; ++kc) {
        const int kof = kc * 64 + gl * 8;
        #pragma unroll
        for (int q = 0; q < 4; ++q) {
            const int r0 = (w * 4 + q) * 8;
            global_to_lds16(Aglob + (size_t)(arow0 + r0 + lr) * 512 + kof, As + r0 * 64);
            global_to_lds16(Bglob + (size_t)(brow0 + r0 + lr) * 512 + kof, Bs + r0 * 64);
        }
        __syncthreads();
        #pragma unroll
        for (int kk = 0; kk < 2; ++kk) {
            bf16x8 a[2], b[8];
            #pragma unroll
            for (int mt = 0; mt < 2; ++mt) {
                const int m = 32 * w + 16 * mt + ln;
                const int g = kk * 4 + lq;
                a[mt] = *(const bf16x8*)(As + m * 64 + ((g ^ ls) * 8));
            }
            #pragma unroll
            for (int nt = 0; nt < 8; ++nt) {
                const int n = 16 * nt + ln;
                const int g = kk * 4 + lq;
                b[nt] = *(const bf16x8*)(Bs + n * 64 + ((g ^ ls) * 8));
            }
            #pragma unroll
            for (int mt = 0; mt < 2; ++mt)
                #pragma unroll
                for (int nt = 0; nt < 8; ++nt)
                    acc[mt][nt] = __builtin_amdgcn_mfma_f32_16x16x32_bf16(
                        a[mt], b[nt], acc[mt][nt], 0, 0, 0);
        }
        __syncthreads();
    }
}

__global__ void __launch_bounds__(256) xg_gemm_kernel(
        const unsigned short* __restrict__ z_bf,
        const unsigned short* __restrict__ Bp_ih,
        const float* __restrict__ biasp,
        float* __restrict__ xg) {
    __shared__ unsigned short As[128 * 64];
    __shared__ unsigned short Bs[128 * 64];
    const int bi = blockIdx.x, j = blockIdx.y;
    const int tid = threadIdx.x, w = tid >> 6, l = tid & 63;
    floatx4 acc[2][8];
    const floatx4 zf = {0.f, 0.f, 0.f, 0.f};
    for (int a1 = 0; a1 < 2; ++a1) for (int a2 = 0; a2 < 8; ++a2) acc[a1][a2] = zf;

    gemm_tile_r1(z_bf, Bp_ih, bi * 128, j * 128, As, Bs, acc, w, l);

    const int ln = l & 15, lq = l >> 4;
    #pragma unroll
    for (int mt = 0; mt < 2; ++mt)
        #pragma unroll
        for (int nt = 0; nt < 8; ++nt) {
            const int colp = j * 128 + nt * 16 + ln;
            const float bv = biasp[colp];
            #pragma unroll
            for (int r = 0; r < 4; ++r) {
                const int b = bi * 128 + 32 * w + 16 * mt + lq * 4 + r;
                xg[(size_t)b * FOURH + colp] = acc[mt][nt][r] + bv;
            }
        }
}

// ---------------------------------------------------------------------------
// A staging: issue 4 sc0/sc1 16B loads (one kc chunk) into VGPRs, no wait.
// LDS sub-layout per kc (8192 ushorts): row r, slot s holds granule s^(r&7).
// ---------------------------------------------------------------------------
__device__ __forceinline__ void stage_issue(const unsigned short* __restrict__ Aglob,
                                            int arow0, int kc, int w, int l,
                                            intx4& t0, intx4& t1, intx4& t2, intx4& t3) {
    const int lr = l >> 3;
    const int gl = (l & 7) ^ lr;
    const int kof = kc * 64 + gl * 8;
    const unsigned short* p0 = Aglob + (size_t)(arow0 + (w * 4 + 0) * 8 + lr) * 512 + kof;
    const unsigned short* p1 = Aglob + (size_t)(arow0 + (w * 4 + 1) * 8 + lr) * 512 + kof;
    const unsigned short* p2 = Aglob + (size_t)(arow0 + (w * 4 + 2) * 8 + lr) * 512 + kof;
    const unsigned short* p3 = Aglob + (size_t)(arow0 + (w * 4 + 3) * 8 + lr) * 512 + kof;
    asm volatile(
        "global_load_dwordx4 %0, %4, off sc0 sc1\n\t"
        "global_load_dwordx4 %1, %5, off sc0 sc1\n\t"
        "global_load_dwordx4 %2, %6, off sc0 sc1\n\t"
        "global_load_dwordx4 %3, %7, off sc0 sc1"
        : "=&v"(t0), "=&v"(t1), "=&v"(t2), "=&v"(t3)
        : "v"(p0), "v"(p1), "v"(p2), "v"(p3)
        : "memory");
}

// Commit a 32 KB chunk (2 kc sub-chunks, 8 regs) after a manual vmcnt wait.
__device__ __forceinline__ void commit8(unsigned short* buf, int w, int l,
                                        const intx4* u) {
    asm volatile("s_waitcnt vmcnt(0)" ::: "memory");
    const int lr = l >> 3, sl = (l & 7) * 8;
    #pragma unroll
    for (int kcL = 0; kcL < 2; ++kcL)
        #pragma unroll
        for (int q = 0; q < 4; ++q)
            *(intx4*)(buf + kcL * 8192 + ((w * 4 + q) * 8 + lr) * 64 + sl) = u[kcL * 4 + q];
}

// ---------------------------------------------------------------------------
// Persistent LSTM. Plain launch, 256 WGs (all co-resident by capacity).
// WG=(bi,j); 16 WGs per bi synced by padded flag cnt[bi*32], RELAXED atomics.
// h passes through the Infinity Cache via sc0/sc1 write-through stores +
// sc0/sc1 bypass loads. K-loop: 4 chunks x 32 KB, double-buffered, loads for
// chunk g+1 in flight across chunk g's MFMA block (1 exposed latency/step).
// ---------------------------------------------------------------------------
__global__ void __launch_bounds__(256, 1) lstm_persistent(
        const unsigned short* __restrict__ Bp_hh,
        const unsigned short* __restrict__ fcw_bf,
        const float* __restrict__ xg,
        const float* __restrict__ fc_b,
        unsigned short* __restrict__ h0b,
        unsigned short* __restrict__ h1b,
        unsigned int* __restrict__ cnt,
        float* __restrict__ out) {
    __shared__ unsigned short AsB0[2 * 8192];  // 32 KiB chunk buf 0 (first 8 KB doubles as hlds)
    __shared__ unsigned short AsB1[2 * 8192];  // 32 KiB chunk buf 1

    const int bx = blockIdx.x;
    const int bi = bx & 15;        // bx%8 == bi%8 for all j -> group L2 locality (perf only)
    const int j  = bx >> 4;
    const int tid = threadIdx.x;
    const int w = tid >> 6, l = tid & 63;
    const int wm = w >> 1, wn = w & 1;
    const int ln = l & 15, lq = l >> 4;
    const bool jlt8 = (j < 8);
    const int j16 = j * 16;
    const int v = 16 * w + ln;
    const float fcb_v = fc_b[v];
    const int arow0 = bi * 128;
    unsigned int* cntp = cnt + bi * 32;        // 128B-padded counters
    const floatx4 zf = {0.f, 0.f, 0.f, 0.f};

    // ---- recurrent-weight fragments in registers (persistent) ----
    // bq[s][nt]: B row n = j*128 + 64*wn + 16*nt + ln, k = 32*s + 8*lq .. +8
    bf16x8 bq[16][4];
    {
        const unsigned short* bbase =
            Bp_hh + ((size_t)(j * 128 + 64 * wn + ln)) * 512 + lq * 8;
        #pragma unroll
        for (int s = 0; s < 16; ++s)
            #pragma unroll
            for (int nt = 0; nt < 4; ++nt)
                bq[s][nt] = *(const bf16x8*)(bbase + (size_t)nt * 16 * 512 + s * 32);
    }

    // ---- x-gate tile into registers ----
    floatx4 xga[4][4];
    #pragma unroll
    for (int mt = 0; mt < 4; ++mt)
        #pragma unroll
        for (int nt = 0; nt < 4; ++nt)
            #pragma unroll
            for (int r = 0; r < 4; ++r) {
                const int b = arow0 + 64 * wm + 16 * mt + lq * 4 + r;
                xga[mt][nt][r] = xg[(size_t)b * FOURH + j * 128 + 64 * wn + 16 * nt + ln];
            }

    // h transpose buffer: overlays AsB0 (dead at epilogue time)
    unsigned short* hlds = AsB0;               // 128 rows x 32 cols ushort = 8 KB

    // ---- t = 0: c0 = 0 -> c = i*g, h = o*tanh(c) ----
    float cst[4][4];
    #pragma unroll
    for (int mt = 0; mt < 4; ++mt)
        #pragma unroll
        for (int r = 0; r < 4; ++r) {
            float iv = sigmoidf_(xga[mt][0][r]);
            float gv = tanhf_  (xga[mt][2][r]);
            float ov = sigmoidf_(xga[mt][3][r]);
            float cv = iv * gv;
            cst[mt][r] = cv;
            hlds[(64 * wm + 16 * mt + lq * 4 + r) * 32 + (wn * 16 + ln)] = f2bf(ov * tanhf_(cv));
        }
    __syncthreads();
    for (int c = tid; c < 512; c += 256) {      // 512 x 16B coherent stores
        const int row = c >> 2, seg = c & 3;
        intx4 d = *(const intx4*)(hlds + row * 32 + seg * 8);
        const unsigned short* p = h0b + (size_t)(arow0 + row) * 512 + j * 32 + seg * 8;
        asm volatile("global_store_dwordx4 %0, %1, off sc0 sc1" :: "v"(p), "v"(d) : "memory");
    }
    asm volatile("s_waitcnt vmcnt(0)" ::: "memory");
    __syncthreads();
    if (tid == 0)
        __hip_atomic_fetch_add(cntp, 1u, __ATOMIC_RELAXED, __HIP_MEMORY_SCOPE_AGENT);

    unsigned short* hb[2] = {h0b, h1b};
    #pragma unroll 1
    for (int t = 1; t < T_; ++t) {
        // wait until all 16 WGs of this bi-group published h_{t-1}
        if (tid == 0) {
            const unsigned int tgt = 16u * (unsigned int)t;
            while (__hip_atomic_fetch_add(cntp, 0u, __ATOMIC_RELAXED,
                                          __HIP_MEMORY_SCOPE_AGENT) < tgt)
                __builtin_amdgcn_s_sleep(2);
        }
        __syncthreads();

        const unsigned short* hprev = hb[(t - 1) & 1];
        unsigned short* hnext = hb[t & 1];

        floatx4 acc[4][4];
        #pragma unroll
        for (int a1 = 0; a1 < 4; ++a1)
            #pragma unroll
            for (int a2 = 0; a2 < 4; ++a2) acc[a1][a2] = zf;
        floatx4 pacc = zf;

        // ---- chunk 0 (kc 0,1): only exposed staging latency of the step ----
        intx4 u[8];
        stage_issue(hprev, arow0, 0, w, l, u[0], u[1], u[2], u[3]);
        stage_issue(hprev, arow0, 1, w, l, u[4], u[5], u[6], u[7]);
        commit8(AsB0, w, l, u);
        __syncthreads();

        #pragma unroll
        for (int g = 0; g < 4; ++g) {
            if (g < 3) {   // loads for chunk g+1 fly across this chunk's MFMA
                stage_issue(hprev, arow0, 2 * g + 2, w, l, u[0], u[1], u[2], u[3]);
                stage_issue(hprev, arow0, 2 * g + 3, w, l, u[4], u[5], u[6], u[7]);
            }
            const unsigned short* buf = (g & 1) ? AsB1 : AsB0;
            #pragma unroll
            for (int ss = 0; ss < 4; ++ss) {
                const int s = g * 4 + ss;
                const int ga = (ss & 1) * 4 + lq;
                const unsigned short* Ac = buf + (ss >> 1) * 8192;
                bf16x8 af[4];
                #pragma unroll
                for (int mt = 0; mt < 4; ++mt) {
                    const int m = 64 * wm + 16 * mt + ln;
                    af[mt] = *(const bf16x8*)(Ac + m * 64 + ((ga ^ (ln & 7)) * 8));
                }
                #pragma unroll
                for (int mt = 0; mt < 4; ++mt)
                    #pragma unroll
                    for (int nt = 0; nt < 4; ++nt)
                        acc[mt][nt] = __builtin_amdgcn_mfma_f32_16x16x32_bf16(
                            af[mt], bq[s][nt], acc[mt][nt], 0, 0, 0);
                if (jlt8) {
                    bf16x8 ap = *(const bf16x8*)(Ac + (j16 + ln) * 64 + ((ga ^ (ln & 7)) * 8));
                    bf16x8 bp = *(const bf16x8*)(fcw_bf + (size_t)v * 512 + s * 32 + lq * 8);
                    pacc = __builtin_amdgcn_mfma_f32_16x16x32_bf16(ap, bp, pacc, 0, 0, 0);
                }
            }
            if (g < 3) {
                commit8((g & 1) ? AsB0 : AsB1, w, l, u);
                __syncthreads();
            }
        }

        // cell update -> h values into LDS transpose buffer (overlay on AsB0;
        // AsB0's last MFMA reader finished before the g=2 end-of-chunk barrier)
        #pragma unroll
        for (int mt = 0; mt < 4; ++mt)
            #pragma unroll
            for (int r = 0; r < 4; ++r) {
                float iv = sigmoidf_(acc[mt][0][r] + xga[mt][0][r]);
                float fv = sigmoidf_(acc[mt][1][r] + xga[mt][1][r]);
                float gv = tanhf_  (acc[mt][2][r] + xga[mt][2][r]);
                float ov = sigmoidf_(acc[mt][3][r] + xga[mt][3][r]);
                float cn = fv * cst[mt][r] + iv * gv;
                cst[mt][r] = cn;
                hlds[(64 * wm + 16 * mt + lq * 4 + r) * 32 + (wn * 16 + ln)] = f2bf(ov * tanhf_(cn));
            }
        __syncthreads();
        for (int c = tid; c < 512; c += 256) {
            const int row = c >> 2, seg = c & 3;
            intx4 d = *(const intx4*)(hlds + row * 32 + seg * 8);
            const unsigned short* p = hnext + (size_t)(arow0 + row) * 512 + j * 32 + seg * 8;
            asm volatile("global_store_dwordx4 %0, %1, off sc0 sc1" :: "v"(p), "v"(d) : "memory");
        }
        asm volatile("s_waitcnt vmcnt(0)" ::: "memory");
        __syncthreads();
        if (tid == 0)
            __hip_atomic_fetch_add(cntp, 1u, __ATOMIC_RELAXED, __HIP_MEMORY_SCOPE_AGENT);

        // projection of h_{t-1} (accumulated in the K-loop) -> out[:, t-1, :]
        if (jlt8) {
            #pragma unroll
            for (int r = 0; r < 4; ++r) {
                const int b = arow0 + j16 + lq * 4 + r;
                out[(size_t)b * (T_ * V_) + (t - 1) * V_ + v] = fmaxf(pacc[r] + fcb_v, 0.0f);
            }
        }
    }

    // ---- final projection of h_{T-1} ----
    if (tid == 0) {
        const unsigned int tgt = 16u * (unsigned int)T_;
        while (__hip_atomic_fetch_add(cntp, 0u, __ATOMIC_RELAXED,
                                      __HIP_MEMORY_SCOPE_AGENT) < tgt)
            __builtin_amdgcn_s_sleep(2);
    }
    __syncthreads();
    if (jlt8) {
        const unsigned short* hlast = hb[(T_ - 1) & 1];
        floatx4 pa = zf;
        const int ar = arow0 + j16 + ln;
        #pragma unroll
        for (int kc = 0; kc < 16; ++kc) {
            const int k = kc * 32 + lq * 8;
            bf16x8 a = load16_sys(hlast + (size_t)ar * 512 + k);   // coherent read
            bf16x8 b = *(const bf16x8*)(fcw_bf + (size_t)v * 512 + k);
            pa = __builtin_amdgcn_mfma_f32_16x16x32_bf16(a, b, pa, 0, 0, 0);
        }
        #pragma unroll
        for (int r = 0; r < 4; ++r) {
            const int b = arow0 + j16 + lq * 4 + r;
            out[(size_t)b * (T_ * V_) + (T_ - 1) * V_ + v] = fmaxf(pa[r] + fcb_v, 0.0f);
        }
    }
}

// ---------------------------------------------------------------------------
extern "C" void kernel_launch(void* const* d_in, const int* in_sizes, int n_in,
                              void* d_out, int out_size, void* d_ws, size_t ws_size,
                              hipStream_t stream) {
    const float* z    = (const float*)d_in[0];
    const float* w_ih = (const float*)d_in[1];
    const float* w_hh = (const float*)d_in[2];
    const float* b_ih = (const float*)d_in[3];
    const float* b_hh = (const float*)d_in[4];
    const float* fc_w = (const float*)d_in[5];
    const float* fc_b = (const float*)d_in[6];
    float* out = (float*)d_out;

    char* ws = (char*)d_ws;
    size_t o = 0;
    auto take = [&](size_t bytes) { char* p = ws + o; o += (bytes + 255) & ~(size_t)255; return p; };
    unsigned short* Bp_hh  = (unsigned short*)take((size_t)FOURH * H_ * 2);
    unsigned short* Bp_ih  = (unsigned short*)take((size_t)FOURH * H_ * 2);
    unsigned short* z_bf   = (unsigned short*)take((size_t)B_ * H_ * 2);
    unsigned short* fcw_bf = (unsigned short*)take((size_t)V_ * H_ * 2);
    float*          biasp  = (float*)take((size_t)FOURH * 4);
    unsigned short* hbuf0  = (unsigned short*)take((size_t)B_ * H_ * 2);
    unsigned short* hbuf1  = (unsigned short*)take((size_t)B_ * H_ * 2);
    unsigned int*   cnt    = (unsigned int*)take(16 * 128);
    float*          xg     = (float*)take((size_t)B_ * FOURH * 4);

    prep_kernel<<<(B_ * H_) / 256, 256, 0, stream>>>(z, w_ih, w_hh, b_ih, b_hh, fc_w,
                                                     Bp_ih, Bp_hh, z_bf, fcw_bf, biasp, cnt);
    xg_gemm_kernel<<<dim3(16, 16), 256, 0, stream>>>(z_bf, Bp_ih, biasp, xg);
    lstm_persistent<<<256, 256, 0, stream>>>(Bp_hh, fcw_bf, xg, fc_b,
                                             hbuf0, hbuf1, cnt, out);
}